// Round 1
// baseline (475.180 us; speedup 1.0000x reference)
//
#include <hip/hip_runtime.h>
#include <hip/hip_bf16.h>

typedef __attribute__((ext_vector_type(8))) short bf16x8;
typedef __attribute__((ext_vector_type(8))) unsigned short ushort8;
typedef __attribute__((ext_vector_type(4))) float f32x4;
typedef unsigned int u32;

#define D_DIM 512
#define C_DIM 1024

__device__ __forceinline__ unsigned short f2bf(float x) {
  u32 u = __float_as_uint(x);
  u32 r = (u + 0x7fffu + ((u >> 16) & 1u)) >> 16;
  return (unsigned short)r;
}

__device__ __forceinline__ void async16(const void* g, void* l) {
  __builtin_amdgcn_global_load_lds(
      (const __attribute__((address_space(1))) u32*)g,
      (__attribute__((address_space(3))) u32*)l, 16, 0, 0);
}

// Normalize rows of length 512 (l2, +1e-12 eps) and cast to bf16.
// One wave per row, 4 rows per block.
__global__ __launch_bounds__(256) void rownorm_kernel(
    const float* __restrict__ src, unsigned short* __restrict__ dst) {
  int row = blockIdx.x * 4 + (threadIdx.x >> 6);
  int lane = threadIdx.x & 63;
  const float* s = src + (size_t)row * D_DIM + lane * 8;
  float4 v0 = *(const float4*)s;
  float4 v1 = *(const float4*)(s + 4);
  float ss = v0.x * v0.x + v0.y * v0.y + v0.z * v0.z + v0.w * v0.w +
             v1.x * v1.x + v1.y * v1.y + v1.z * v1.z + v1.w * v1.w;
#pragma unroll
  for (int m = 32; m >= 1; m >>= 1) ss += __shfl_xor(ss, m);
  float rinv = rsqrtf(ss + 1e-12f);
  float tv[8] = {v0.x, v0.y, v0.z, v0.w, v1.x, v1.y, v1.z, v1.w};
  ushort8 o;
#pragma unroll
  for (int i = 0; i < 8; ++i) o[i] = f2bf(tv[i] * rinv);
  *(ushort8*)(dst + (size_t)row * D_DIM + lane * 8) = o;
}

// vbT[n][k] = bf16(val[k][n])  (transpose+cast, 32x32 LDS tiles)
__global__ __launch_bounds__(256) void valT_kernel(
    const float* __restrict__ val, unsigned short* __restrict__ vbT) {
  __shared__ float tile[32][33];
  int bx = blockIdx.x & 31;  // n tile
  int by = blockIdx.x >> 5;  // k tile
  int t = threadIdx.x;
  int r = t >> 5, c = t & 31;
#pragma unroll
  for (int i = 0; i < 4; ++i)
    tile[r + i * 8][c] = val[(size_t)(by * 32 + r + i * 8) * C_DIM + bx * 32 + c];
  __syncthreads();
#pragma unroll
  for (int i = 0; i < 4; ++i)
    vbT[(size_t)(bx * 32 + r + i * 8) * C_DIM + by * 32 + c] = f2bf(tile[c][r + i * 8]);
}

// C = A(MxK, bf16, row-major) * B^T(NxK, bf16, row-major); 128x128 tile, BK=32,
// 4 waves in 2x2, each wave 4x4 16x16x32 MFMA tiles, double-buffered
// global_load_lds staging (m97 structure).
// SHARP epilogue: s = sigmoid(10x-5)+sigmoid(-10x-5); write w bf16, atomicAdd row sums.
// !SHARP epilogue: write acc * (1/rsum[row]) as f32.
template <int K, bool SHARP>
__global__ __launch_bounds__(256) void gemm_kernel(
    const unsigned short* __restrict__ A, const unsigned short* __restrict__ Bm,
    unsigned short* __restrict__ wout, float* __restrict__ rsum,
    float* __restrict__ fout) {
  __shared__ unsigned short smA[2][128 * 32];
  __shared__ unsigned short smB[2][128 * 32];
  const int NT = C_DIM / 128;  // 8 n-tiles
  int m0 = (blockIdx.x / NT) * 128;
  int n0 = (blockIdx.x % NT) * 128;
  int t = threadIdx.x;
  int lane = t & 63;
  int wv = t >> 6;
  int wm = (wv >> 1) * 64;
  int wn = (wv & 1) * 64;

  f32x4 acc[4][4];
#pragma unroll
  for (int i = 0; i < 4; ++i)
#pragma unroll
    for (int j = 0; j < 4; ++j) acc[i][j] = (f32x4){0.f, 0.f, 0.f, 0.f};

  auto stage = [&](int buf, int k0) {
#pragma unroll
    for (int i = 0; i < 2; ++i) {
      int c = i * 256 + t;
      int row = c >> 2, cc = c & 3;
      async16(A + (size_t)(m0 + row) * K + k0 + cc * 8, &smA[buf][c * 8]);
      async16(Bm + (size_t)(n0 + row) * K + k0 + cc * 8, &smB[buf][c * 8]);
    }
  };

  stage(0, 0);
  __syncthreads();
  const int NK = K / 32;
#pragma unroll 2
  for (int kt = 0; kt < NK; ++kt) {
    int cur = kt & 1;
    if (kt + 1 < NK) stage(cur ^ 1, (kt + 1) * 32);
    bf16x8 a[4], b[4];
    int kg = (lane >> 4) * 8;
#pragma unroll
    for (int i = 0; i < 4; ++i) {
      a[i] = *(const bf16x8*)&smA[cur][(wm + i * 16 + (lane & 15)) * 32 + kg];
      b[i] = *(const bf16x8*)&smB[cur][(wn + i * 16 + (lane & 15)) * 32 + kg];
    }
#pragma unroll
    for (int i = 0; i < 4; ++i)
#pragma unroll
      for (int j = 0; j < 4; ++j)
        acc[i][j] = __builtin_amdgcn_mfma_f32_16x16x32_bf16(a[i], b[j], acc[i][j], 0, 0, 0);
    __syncthreads();
  }

  int rbase = m0 + wm + ((lane >> 4) << 2);
  int cbase = n0 + wn + (lane & 15);

  if (SHARP) {
    float rs[4][4];
#pragma unroll
    for (int i = 0; i < 4; ++i)
#pragma unroll
      for (int j = 0; j < 4; ++j) rs[i][j] = 0.f;
#pragma unroll
    for (int mi = 0; mi < 4; ++mi)
#pragma unroll
      for (int ni = 0; ni < 4; ++ni) {
#pragma unroll
        for (int j = 0; j < 4; ++j) {
          float x = acc[mi][ni][j];
          float s = 1.f / (1.f + __expf(5.f - 10.f * x)) +
                    1.f / (1.f + __expf(5.f + 10.f * x));
          rs[mi][j] += s;
          wout[(size_t)(rbase + mi * 16 + j) * C_DIM + (cbase + ni * 16)] = f2bf(s);
        }
      }
#pragma unroll
    for (int mi = 0; mi < 4; ++mi)
#pragma unroll
      for (int j = 0; j < 4; ++j) {
        float v = rs[mi][j];
        v += __shfl_xor(v, 1);
        v += __shfl_xor(v, 2);
        v += __shfl_xor(v, 4);
        v += __shfl_xor(v, 8);
        if ((lane & 15) == 0) atomicAdd(&rsum[rbase + mi * 16 + j], v);
      }
  } else {
    float rinv[4][4];
#pragma unroll
    for (int mi = 0; mi < 4; ++mi)
#pragma unroll
      for (int j = 0; j < 4; ++j)
        rinv[mi][j] = 1.f / rsum[rbase + mi * 16 + j];
#pragma unroll
    for (int mi = 0; mi < 4; ++mi)
#pragma unroll
      for (int ni = 0; ni < 4; ++ni)
#pragma unroll
        for (int j = 0; j < 4; ++j)
          fout[(size_t)(rbase + mi * 16 + j) * C_DIM + cbase + ni * 16] =
              acc[mi][ni][j] * rinv[mi][j];
  }
}

extern "C" void kernel_launch(void* const* d_in, const int* in_sizes, int n_in,
                              void* d_out, int out_size, void* d_ws, size_t ws_size,
                              hipStream_t stream) {
  const float* query = (const float*)d_in[0];
  const float* key = (const float*)d_in[1];
  const float* val = (const float*)d_in[2];
  float* out = (float*)d_out;
  const int B = in_sizes[0] / D_DIM;  // 65536

  // workspace layout (196 MB total)
  char* ws = (char*)d_ws;
  unsigned short* kb = (unsigned short*)(ws);                    // 1 MB
  unsigned short* vbT = (unsigned short*)(ws + (1ull << 20));    // 2 MB
  float* rsum = (float*)(ws + 3ull * (1ull << 20));              // 256 KB
  unsigned short* qb = (unsigned short*)(ws + 4ull * (1ull << 20));   // 64 MB
  unsigned short* wbf = (unsigned short*)(ws + 68ull * (1ull << 20)); // 128 MB

  rownorm_kernel<<<dim3(B / 4), dim3(256), 0, stream>>>(query, qb);
  rownorm_kernel<<<dim3(C_DIM / 4), dim3(256), 0, stream>>>(key, kb);
  valT_kernel<<<dim3(1024), dim3(256), 0, stream>>>(val, vbT);
  hipMemsetAsync(rsum, 0, (size_t)B * sizeof(float), stream);

  dim3 grid((B / 128) * (C_DIM / 128));
  gemm_kernel<D_DIM, true><<<grid, dim3(256), 0, stream>>>(qb, kb, wbf, rsum, nullptr);
  gemm_kernel<C_DIM, false><<<grid, dim3(256), 0, stream>>>(wbf, vbT, nullptr, rsum, out);
}